// Round 10
// baseline (461.551 us; speedup 1.0000x reference)
//
#include <hip/hip_runtime.h>

#define NB 8192
#define NT 512

typedef unsigned int u32;
typedef unsigned short u16;
typedef float f32x2 __attribute__((ext_vector_type(2)));
typedef _Float16 h16x2 __attribute__((ext_vector_type(2)));

__device__ __forceinline__ float rcp_(float x){ return __builtin_amdgcn_rcpf(x); }
__device__ __forceinline__ float exp2_(float x){ return __builtin_amdgcn_exp2f(x); }
// tanh(x) = 1 - 2/(1+exp2(2x*log2e)); saturates correctly at +/-inf.
__device__ __forceinline__ float tanh_(float x){ return 1.0f - 2.0f*rcp_(1.0f + exp2_(2.88539008177792681f*x)); }

// Pin a value into a VGPR (defeats per-iteration rematerialization/reload).
#define PINF(v)  asm volatile("" : "+v"(v))

// quad_perm DPP ctrl = p0|p1<<2|p2<<4|p3<<6 (dst lane k reads src lane p_k)
#define QP_XOR2 0x4E   // [2,3,0,1]
#define QP_ROT1 0x39   // [1,2,3,0]  (lane k reads k+1)
#define QP_ROT3 0x93   // [3,0,1,2]
#define QP_BC0  0x00   // all read lane 0
#define QP_BC1  0x55   // all read lane 1
#define QP_BC3  0xFF   // all read lane 3
template<int C>
__device__ __forceinline__ float dppf(float x){
    return __int_as_float(__builtin_amdgcn_update_dpp(0, __float_as_int(x), C, 0xF, 0xF, true));
}
// lane^4 exchange, pure VALU (no LDS). DPP convention (per AMD DPP prefix-scan
// idiom): row_shr:N reads lane i-N, row_shl:N reads lane i+N.
//   lanes 0-3 / 8-11 (banks 0,2; mask 0x5) need i+4 -> row_shl:4 (0x104)
//   lanes 4-7 /12-15 (banks 1,3; mask 0xA) need i-4 -> row_shr:4 (0x114)
__device__ __forceinline__ float swz4(float x){
    int v = __builtin_amdgcn_update_dpp(__float_as_int(x), __float_as_int(x), 0x104, 0xF, 0x5, false);
    v     = __builtin_amdgcn_update_dpp(v,                 __float_as_int(x), 0x114, 0xF, 0xA, false);
    return __int_as_float(v);
}
__device__ __forceinline__ void pkfma(f32x2& acc, f32x2 a, f32x2 b){
    asm("v_pk_fma_f32 %0, %1, %2, %0" : "+v"(acc) : "v"(a), "v"(b));
}
__device__ __forceinline__ f32x2 pkmul(f32x2 a, f32x2 b){
    f32x2 d; asm("v_pk_mul_f32 %0, %1, %2" : "=v"(d) : "v"(a), "v"(b)); return d;
}

__device__ __forceinline__ float upkh(u16 v){ _Float16 h; __builtin_memcpy(&h,&v,2); return (float)h; }
__device__ __forceinline__ float upk_lo(u32 v){ return upkh((u16)(v&0xffffu)); }
__device__ __forceinline__ float upk_hi(u32 v){ return upkh((u16)(v>>16)); }

__device__ __forceinline__ float dot2f(h16x2 a, h16x2 b, float c){
#if __has_builtin(__builtin_amdgcn_fdot2)
    return __builtin_amdgcn_fdot2(a, b, c, false);
#else
    return fmaf((float)a.x, (float)b.x, fmaf((float)a.y, (float)b.y, c));
#endif
}

// ---------------------------------------------------------------------------
// 8-lane-per-sequence layout: q = lane&7; gate g = q&3 (0=i,1=f,2=g,3=o);
// hidden half m = q>>2 (owns indices 3m..3m+2). Lanes 0-3 form a DPP quad
// (half m=0), lanes 4-7 the next quad (m=1).
// cell_update via quad broadcasts (no select masks):
//   xor2 pairs lane0<->2 (i,g) and lane1<->3 (f,o):
//     u = a * dpp_xor2(a)  -> lanes {0,2} hold i*g
//     fc = a * c           -> lane 1 holds f*c
//     c  = bcast0(u) + bcast1(fc)
//     ov = bcast3(a)       -> o
//   tanh(c) computed once per lane (lane g does c[g<3?g:0]) and gathered by
//   quad rotations.
// ---------------------------------------------------------------------------
__device__ __forceinline__ void cell_update(const float a[3], float c[3], float ho[3], int g){
    float ov[3];
#pragma unroll
    for (int i=0;i<3;++i){
        const float t   = dppf<QP_XOR2>(a[i]);
        const float u   = a[i]*t;            // lanes 0,2: i*g
        const float ig  = dppf<QP_BC0>(u);
        const float fc  = a[i]*c[i];         // lane 1: f*c
        const float fcb = dppf<QP_BC1>(fc);
        c[i]  = ig + fcb;
        ov[i] = dppf<QP_BC3>(a[i]);          // o
    }
    const float cg = (g==1) ? c[1] : ((g==2) ? c[2] : c[0]);
    const float tg = tanh_(cg);
    const float w1 = dppf<QP_ROT1>(tg);      // from lane (g+1)&3
    const float w2 = dppf<QP_XOR2>(tg);      // from lane (g+2)&3
    const float w3 = dppf<QP_ROT3>(tg);      // from lane (g+3)&3
#pragma unroll
    for (int j=0;j<3;++j){
        const int r = (j - g) & 3;           // rotation distance to lane j
        const float lo = (r & 1) ? w1 : tg;
        const float hi = (r & 1) ? w3 : w2;
        ho[j] = ov[j] * ((r & 2) ? hi : lo);
    }
}

// ---------------------------------------------------------------------------
// Layer 0, both directions. 2048 waves (2/SIMD). Outputs fp16, separate
// fwd/bwd regions, 12B per (t,seq) slot:
//   dword@0=(h0,h1) [m=0], dword@4=(h3,h4) [m=1], u16@8=h2, u16@10=h5
// ---------------------------------------------------------------------------
__global__ __launch_bounds__(64)
__attribute__((amdgpu_waves_per_eu(2,2)))
void lstm_l0_g8(
    const float* __restrict__ x,
    const float* __restrict__ h0, const float* __restrict__ c0,
    const float* __restrict__ Wf, const float* __restrict__ Uf, const float* __restrict__ bf,
    const float* __restrict__ Wb, const float* __restrict__ Ub, const float* __restrict__ bb,
    char* __restrict__ fbuf, char* __restrict__ bbuf)
{
    const int tid = blockIdx.x*64 + threadIdx.x;
    const int q   = tid & 7;
    const int e   = tid >> 3;
    const int b   = e & (NB-1);
    const int dir = e >> 13;
    const int g   = q & 3;
    const int m   = q >> 2;

    const float* W  = dir ? Wb : Wf;
    const float* U  = dir ? Ub : Uf;
    const float* bi = dir ? bb : bf;

    const float cE = (g==2) ? -2.88539008177792681f : -1.44269504088896341f;
    const float cM = (g==2) ? 2.0f : 1.0f;
    const float cB = (g==2) ? -1.0f : 0.0f;

    f32x2 Wx2[3][3], Uh2[3][3];
    float cEb[3];
#pragma unroll
    for (int i=0;i<3;++i){
        const int r = g*6 + 3*m + i;
#pragma unroll
        for (int k=0;k<3;++k) Wx2[i][k] = f32x2{W[r*6+2*k], W[r*6+2*k+1]};
        Uh2[i][0] = f32x2{U[r*6+3*m+0],     U[r*6+3*m+1]};
        Uh2[i][1] = f32x2{U[r*6+3*m+2],     U[r*6+3*(1-m)+0]};
        Uh2[i][2] = f32x2{U[r*6+3*(1-m)+1], U[r*6+3*(1-m)+2]};
        cEb[i] = cE * bi[r];
    }
#pragma unroll
    for (int i=0;i<3;++i){
#pragma unroll
        for (int k=0;k<3;++k){ PINF(Wx2[i][k]); PINF(Uh2[i][k]); }
        PINF(cEb[i]);
    }

    float ho[3], hx[3], cc[3];
    {
        const int base = dir*(NB*6) + b*6;
#pragma unroll
        for (int i=0;i<3;++i){
            ho[i] = h0[base+3*m+i];
            hx[i] = h0[base+3*(1-m)+i];
            cc[i] = c0[base+3*m+i];
        }
    }

    const float* xb = x + (size_t)b*(NT*6);
    const int dt = dir ? -1 : 1;
    int t = dir ? (NT-1) : 0;

    const size_t tstr = (size_t)NB*12;
    char* op = (dir ? bbuf : fbuf) + (size_t)b*12 + (size_t)t*tstr;
    const ptrdiff_t dop = (ptrdiff_t)dt * (ptrdiff_t)tstr;

    f32x2 xA[3], xB[3];
    auto ldx = [&](int tt, f32x2* d){
        const f32x2* p = (const f32x2*)(xb + tt*6);
        d[0]=p[0]; d[1]=p[1]; d[2]=p[2];
    };
    ldx(t, xA); ldx(t+dt, xB);

    auto STEP = [&](f32x2* xv){
        f32x2 h2_0{ho[0],ho[1]}, h2_1{ho[2],hx[0]}, h2_2{hx[1],hx[2]};
        float a[3];
#pragma unroll
        for (int i=0;i<3;++i){
            f32x2 acc = pkmul(Wx2[i][0], xv[0]);
            pkfma(acc, Wx2[i][1], xv[1]);
            pkfma(acc, Wx2[i][2], xv[2]);
            pkfma(acc, Uh2[i][0], h2_0);
            pkfma(acc, Uh2[i][1], h2_1);
            pkfma(acc, Uh2[i][2], h2_2);
            const float s = acc.x + acc.y;
            const float arg = fmaf(cE, s, cEb[i]);
            a[i] = fmaf(cM, rcp_(1.0f + exp2_(arg)), cB);
        }
        cell_update(a, cc, ho, g);
#pragma unroll
        for (int i=0;i<3;++i) hx[i] = swz4(ho[i]);
        if (g == 0){
            auto p01 = __builtin_amdgcn_cvt_pkrtz(ho[0], ho[1]);
            *(u32*)(op + 4*m) = __builtin_bit_cast(u32, p01);
            _Float16 h2v = (_Float16)ho[2];
            *(u16*)(op + 8 + 2*m) = __builtin_bit_cast(u16, h2v);
        }
    };

    for (int s=0; s<NT; s+=2){
        STEP(xA);
        { int tp = t + 2*dt; tp = tp<0?0:(tp>NT-1?NT-1:tp); ldx(tp, xA); }
        t += dt; op += dop;
        STEP(xB);
        { int tp = t + 2*dt; tp = tp<0?0:(tp>NT-1?NT-1:tp); ldx(tp, xB); }
        t += dt; op += dop;
    }
}

// ---------------------------------------------------------------------------
// Layer 1 forward scan (fp16 inputs consumed directly via v_dot2_f32_f16),
// + single r1 step + FC head. 1024 waves = 1/SIMD.
// ---------------------------------------------------------------------------
__global__ __launch_bounds__(64)
__attribute__((amdgpu_waves_per_eu(1,1)))
void lstm_l1_g8(
    const char* __restrict__ fbuf, const char* __restrict__ bbuf,
    const float* __restrict__ h0, const float* __restrict__ c0,
    const float* __restrict__ W1f, const float* __restrict__ U1f, const float* __restrict__ b1f,
    const float* __restrict__ W1b, const float* __restrict__ U1b, const float* __restrict__ b1b,
    const float* __restrict__ fcw, const float* __restrict__ fcb,
    float* __restrict__ out)
{
    const int tid = blockIdx.x*64 + threadIdx.x;
    const int q = tid & 7;
    const int b = tid >> 3;
    const int g = q & 3;
    const int m = q >> 2;

    const float cE = (g==2) ? -2.88539008177792681f : -1.44269504088896341f;
    const float cM = (g==2) ? 2.0f : 1.0f;
    const float cB = (g==2) ? -1.0f : 0.0f;

    // fp16 weight pairs ordered to match the stored dwords:
    // fwd dwords: (c0,c1),(c3,c4),(c2,c5); bwd dwords: (c6,c7),(c9,c10),(c8,c11)
    h16x2 wh[3][6];
    f32x2 Uh2[3][3];
    float cEb[3];
#pragma unroll
    for (int i=0;i<3;++i){
        const int r = g*6 + 3*m + i;
        const float* Wr = W1f + r*12;
#pragma unroll
        for (int k=0;k<6;++k){
            const int c0i = (k==0)?0:(k==1)?3:(k==2)?2:(k==3)?6:(k==4)?9:8;
            const int c1i = (k==0)?1:(k==1)?4:(k==2)?5:(k==3)?7:(k==4)?10:11;
            h16x2 v; v.x = (_Float16)Wr[c0i]; v.y = (_Float16)Wr[c1i];
            wh[i][k] = v;
        }
        Uh2[i][0] = f32x2{U1f[r*6+3*m+0],     U1f[r*6+3*m+1]};
        Uh2[i][1] = f32x2{U1f[r*6+3*m+2],     U1f[r*6+3*(1-m)+0]};
        Uh2[i][2] = f32x2{U1f[r*6+3*(1-m)+1], U1f[r*6+3*(1-m)+2]};
        cEb[i] = cE * b1f[r];
    }
#pragma unroll
    for (int i=0;i<3;++i){
#pragma unroll
        for (int k=0;k<6;++k) PINF(wh[i][k]);
#pragma unroll
        for (int k=0;k<3;++k) PINF(Uh2[i][k]);
        PINF(cEb[i]);
    }

    float ho[3], hx[3], cc[3];
    {
        const int base = 2*(NB*6) + b*6;
#pragma unroll
        for (int i=0;i<3;++i){
            ho[i] = h0[base+3*m+i];
            hx[i] = h0[base+3*(1-m)+i];
            cc[i] = c0[base+3*m+i];
        }
    }

    const char* pf = fbuf + (size_t)b*12;
    const char* pb = bbuf + (size_t)b*12;
    const size_t tstr = (size_t)NB*12;

    u32 dA[6], dB[6];
    auto loadD = [&](int tt, u32* d){
        const u32* f = (const u32*)(pf + (size_t)tt*tstr);
        const u32* r = (const u32*)(pb + (size_t)tt*tstr);
        d[0]=f[0]; d[1]=f[1]; d[2]=f[2]; d[3]=r[0]; d[4]=r[1]; d[5]=r[2];
    };

    auto STEP = [&](u32* d){
        f32x2 h2_0{ho[0],ho[1]}, h2_1{ho[2],hx[0]}, h2_2{hx[1],hx[2]};
        float a[3];
#pragma unroll
        for (int i=0;i<3;++i){
            float s = dot2f(wh[i][0], __builtin_bit_cast(h16x2, d[0]), 0.0f);
#pragma unroll
            for (int k=1;k<6;++k)
                s = dot2f(wh[i][k], __builtin_bit_cast(h16x2, d[k]), s);
            f32x2 acc = pkmul(Uh2[i][0], h2_0);
            pkfma(acc, Uh2[i][1], h2_1);
            pkfma(acc, Uh2[i][2], h2_2);
            const float z = s + acc.x + acc.y;
            const float arg = fmaf(cE, z, cEb[i]);
            a[i] = fmaf(cM, rcp_(1.0f + exp2_(arg)), cB);
        }
        cell_update(a, cc, ho, g);
#pragma unroll
        for (int i=0;i<3;++i) hx[i] = swz4(ho[i]);
    };

    loadD(0, dA); loadD(1, dB);
    for (int t=0; t<NT; t+=2){
        STEP(dA);
        { int tp = t+2; tp = tp>NT-1?NT-1:tp; loadD(tp, dA); }
        STEP(dB);
        { int tp = t+3; tp = tp>NT-1?NT-1:tp; loadD(tp, dB); }
    }
    // dB holds l0[NT-1]; (ho,hx) == f1[NT-1]

    float in[12];
    in[0]=upk_lo(dB[0]); in[1]=upk_hi(dB[0]); in[3]=upk_lo(dB[1]);
    in[4]=upk_hi(dB[1]); in[2]=upk_lo(dB[2]); in[5]=upk_hi(dB[2]);
    in[6]=upk_lo(dB[3]); in[7]=upk_hi(dB[3]); in[9]=upk_lo(dB[4]);
    in[10]=upk_hi(dB[4]); in[8]=upk_lo(dB[5]); in[11]=upk_hi(dB[5]);

    // ---- r1: single reverse-direction step at t = NT-1 ----
    const int base3 = 3*(NB*6) + b*6;
    float hr[6];
#pragma unroll
    for (int j=0;j<6;++j) hr[j] = h0[base3 + j];
    float cr[3];
#pragma unroll
    for (int i=0;i<3;++i) cr[i] = c0[base3 + 3*m + i];

    float a[3];
#pragma unroll
    for (int i=0;i<3;++i){
        const int r = g*6 + 3*m + i;
        float acc = b1b[r];
#pragma unroll
        for (int k=0;k<12;++k) acc = fmaf(W1b[r*12+k], in[k], acc);
#pragma unroll
        for (int j=0;j<6;++j)  acc = fmaf(U1b[r*6+j], hr[j], acc);
        a[i] = fmaf(cM, rcp_(1.0f + exp2_(cE*acc)), cB);
    }
    float r1o[3];
    cell_update(a, cr, r1o, g);
    float r1x[3];
#pragma unroll
    for (int i=0;i<3;++i) r1x[i] = swz4(r1o[i]);

    // ---- head ----
    if (g == 0){
#pragma unroll
        for (int i=0;i<3;++i){
            const int r = 3*m + i;
            float acc = fcb[r];
#pragma unroll
            for (int k=0;k<3;++k){
                acc = fmaf(fcw[r*12 + 3*m + k],         fmaxf(ho[k],0.f), acc);
                acc = fmaf(fcw[r*12 + 3*(1-m) + k],     fmaxf(hx[k],0.f), acc);
                acc = fmaf(fcw[r*12 + 6 + 3*m + k],     fmaxf(r1o[k],0.f), acc);
                acc = fmaf(fcw[r*12 + 6 + 3*(1-m) + k], fmaxf(r1x[k],0.f), acc);
            }
            out[b*6 + r] = acc;
        }
    }
}

extern "C" void kernel_launch(void* const* d_in, const int* in_sizes, int n_in,
                              void* d_out, int out_size, void* d_ws, size_t ws_size,
                              hipStream_t stream)
{
    (void)in_sizes; (void)n_in; (void)out_size; (void)ws_size;
    const float* x    = (const float*)d_in[0];
    const float* h0   = (const float*)d_in[1];
    const float* c0   = (const float*)d_in[2];
    const float* W0f  = (const float*)d_in[3];
    const float* U0f  = (const float*)d_in[4];
    const float* b0f  = (const float*)d_in[5];
    const float* W0b  = (const float*)d_in[6];
    const float* U0b  = (const float*)d_in[7];
    const float* b0b  = (const float*)d_in[8];
    const float* W1f  = (const float*)d_in[9];
    const float* U1f  = (const float*)d_in[10];
    const float* b1f  = (const float*)d_in[11];
    const float* W1b  = (const float*)d_in[12];
    const float* U1b  = (const float*)d_in[13];
    const float* b1b  = (const float*)d_in[14];
    const float* fcw  = (const float*)d_in[15];
    const float* fcb  = (const float*)d_in[16];
    float* out = (float*)d_out;
    char* ws = (char*)d_ws;

    char* fbuf = ws;
    char* bbuf = ws + (size_t)NT*NB*12;

    lstm_l0_g8<<<dim3(2048), dim3(64), 0, stream>>>(x, h0, c0, W0f, U0f, b0f, W0b, U0b, b0b, fbuf, bbuf);
    lstm_l1_g8<<<dim3(1024), dim3(64), 0, stream>>>(fbuf, bbuf, h0, c0, W1f, U1f, b1f, W1b, U1b, b1b, fcw, fcb, out);
}

// Round 11
// 365.286 us; speedup vs baseline: 1.2635x; 1.2635x over previous
//
#include <hip/hip_runtime.h>

#define NB 8192
#define NT 512

typedef unsigned int u32;
typedef unsigned short u16;
typedef float f32x2 __attribute__((ext_vector_type(2)));
typedef u32 u32x3 __attribute__((ext_vector_type(3)));
typedef _Float16 h16x2 __attribute__((ext_vector_type(2)));

__device__ __forceinline__ float rcp_(float x){ return __builtin_amdgcn_rcpf(x); }
__device__ __forceinline__ float exp2_(float x){ return __builtin_amdgcn_exp2f(x); }
__device__ __forceinline__ float tanh_(float x){ return 1.0f - 2.0f*rcp_(1.0f + exp2_(2.88539008177792681f*x)); }

#define PINF(v)  asm volatile("" : "+v"(v))

// quad_perm DPP ctrl = p0|p1<<2|p2<<4|p3<<6 (dst lane k reads src lane p_k)
#define QP_XOR2 0x4E
#define QP_ROT1 0x39
#define QP_ROT3 0x93
#define QP_BC0  0x00
#define QP_BC1  0x55
#define QP_BC3  0xFF
template<int C>
__device__ __forceinline__ float dppf(float x){
    return __int_as_float(__builtin_amdgcn_update_dpp(0, __float_as_int(x), C, 0xF, 0xF, true));
}
// lane^4 exchange, pure VALU (validated R10)
__device__ __forceinline__ float swz4(float x){
    int v = __builtin_amdgcn_update_dpp(__float_as_int(x), __float_as_int(x), 0x104, 0xF, 0x5, false);
    v     = __builtin_amdgcn_update_dpp(v,                 __float_as_int(x), 0x114, 0xF, 0xA, false);
    return __int_as_float(v);
}
__device__ __forceinline__ void pkfma(f32x2& acc, f32x2 a, f32x2 b){
    asm("v_pk_fma_f32 %0, %1, %2, %0" : "+v"(acc) : "v"(a), "v"(b));
}
__device__ __forceinline__ f32x2 pkmul(f32x2 a, f32x2 b){
    f32x2 d; asm("v_pk_mul_f32 %0, %1, %2" : "=v"(d) : "v"(a), "v"(b)); return d;
}

__device__ __forceinline__ float upkh(u16 v){ _Float16 h; __builtin_memcpy(&h,&v,2); return (float)h; }
__device__ __forceinline__ float upk_lo(u32 v){ return upkh((u16)(v&0xffffu)); }
__device__ __forceinline__ float upk_hi(u32 v){ return upkh((u16)(v>>16)); }
__device__ __forceinline__ u32 pkrtz(float a, float b){
    auto p = __builtin_amdgcn_cvt_pkrtz(a, b);
    return __builtin_bit_cast(u32, p);
}

__device__ __forceinline__ float dot2f(h16x2 a, h16x2 b, float c){
#if __has_builtin(__builtin_amdgcn_fdot2)
    return __builtin_amdgcn_fdot2(a, b, c, false);
#else
    return fmaf((float)a.x, (float)b.x, fmaf((float)a.y, (float)b.y, c));
#endif
}
__device__ __forceinline__ float dot2u(u32 w, u32 d, float c){
    return dot2f(__builtin_bit_cast(h16x2, w), __builtin_bit_cast(h16x2, d), c);
}

// v_perm_b32 selectors: __builtin_amdgcn_perm(a, b, sel): sel byte 0-3 -> b bytes, 4-7 -> a bytes
#define SEL_LL 0x05040100u  // (lo16 b) | (lo16 a)<<16
#define SEL_HL 0x05040302u  // (hi16 b) | (lo16 a)<<16
#define SEL_HH 0x07060302u  // (hi16 b) | (hi16 a)<<16

// ---------------------------------------------------------------------------
// 8-lane-per-seq layout: q=lane&7; gate g=q&3 (0=i,1=f,2=g,3=o); half m=q>>2.
// cell_update via quad broadcasts (validated R10).
// ---------------------------------------------------------------------------
__device__ __forceinline__ void cell_update(const float a[3], float c[3], float ho[3], int g){
    float ov[3];
#pragma unroll
    for (int i=0;i<3;++i){
        const float t   = dppf<QP_XOR2>(a[i]);
        const float u   = a[i]*t;
        const float ig  = dppf<QP_BC0>(u);
        const float fc  = a[i]*c[i];
        const float fcb = dppf<QP_BC1>(fc);
        c[i]  = ig + fcb;
        ov[i] = dppf<QP_BC3>(a[i]);
    }
    const float cg = (g==1) ? c[1] : ((g==2) ? c[2] : c[0]);
    const float tg = tanh_(cg);
    const float w1 = dppf<QP_ROT1>(tg);
    const float w2 = dppf<QP_XOR2>(tg);
    const float w3 = dppf<QP_ROT3>(tg);
#pragma unroll
    for (int j=0;j<3;++j){
        const int r = (j - g) & 3;
        const float lo = (r & 1) ? w1 : tg;
        const float hi = (r & 1) ? w3 : w2;
        ho[j] = ov[j] * ((r & 2) ? hi : lo);
    }
}

// ---------------------------------------------------------------------------
// Layer 0, both directions. 2048 waves (2/SIMD).
// NEW output layout (fp16, per direction): 24B per (t-pair, seq):
//   lane(g==0,m) stores dwordx3 at [t2][seq][m]:
//     d0 = pk(h[3m+0]@E, h[3m+1]@E)
//     d1 = pk(h[3m+2]@E, h[3m+0]@O)
//     d2 = pk(h[3m+1]@O, h[3m+2]@O)
//   where E = even timestep of the pair (t), O = odd (t+1), regardless of dir.
// One dwordx3 store per 2 steps; NO sub-dword stores.
// ---------------------------------------------------------------------------
__global__ __launch_bounds__(64)
__attribute__((amdgpu_waves_per_eu(2,2)))
void lstm_l0_g8(
    const float* __restrict__ x,
    const float* __restrict__ h0, const float* __restrict__ c0,
    const float* __restrict__ Wf, const float* __restrict__ Uf, const float* __restrict__ bf,
    const float* __restrict__ Wb, const float* __restrict__ Ub, const float* __restrict__ bb,
    char* __restrict__ fbuf, char* __restrict__ bbuf)
{
    const int tid = blockIdx.x*64 + threadIdx.x;
    const int q   = tid & 7;
    const int e   = tid >> 3;
    const int b   = e & (NB-1);
    const int dir = e >> 13;
    const int g   = q & 3;
    const int m   = q >> 2;

    const float* W  = dir ? Wb : Wf;
    const float* U  = dir ? Ub : Uf;
    const float* bi = dir ? bb : bf;

    const float cE = (g==2) ? -2.88539008177792681f : -1.44269504088896341f;
    const float cM = (g==2) ? 2.0f : 1.0f;
    const float cB = (g==2) ? -1.0f : 0.0f;

    f32x2 Wx2[3][3], Uh2[3][3];
    float cEb[3];
#pragma unroll
    for (int i=0;i<3;++i){
        const int r = g*6 + 3*m + i;
#pragma unroll
        for (int k=0;k<3;++k) Wx2[i][k] = f32x2{W[r*6+2*k], W[r*6+2*k+1]};
        Uh2[i][0] = f32x2{U[r*6+3*m+0],     U[r*6+3*m+1]};
        Uh2[i][1] = f32x2{U[r*6+3*m+2],     U[r*6+3*(1-m)+0]};
        Uh2[i][2] = f32x2{U[r*6+3*(1-m)+1], U[r*6+3*(1-m)+2]};
        cEb[i] = cE * bi[r];
    }
#pragma unroll
    for (int i=0;i<3;++i){
#pragma unroll
        for (int k=0;k<3;++k){ PINF(Wx2[i][k]); PINF(Uh2[i][k]); }
        PINF(cEb[i]);
    }

    float ho[3], hx[3], cc[3];
    {
        const int base = dir*(NB*6) + b*6;
#pragma unroll
        for (int i=0;i<3;++i){
            ho[i] = h0[base+3*m+i];
            hx[i] = h0[base+3*(1-m)+i];
            cc[i] = c0[base+3*m+i];
        }
    }

    const f32x2* xp = (const f32x2*)(x + (size_t)b*(NT*6));  // 3 f32x2 per step
    const int dt = dir ? -1 : 1;

    const size_t tstr2 = (size_t)NB*24;
    char* op = (dir ? bbuf : fbuf) + (size_t)b*24 + m*12 + (size_t)(dir ? (NT/2-1) : 0)*tstr2;
    const ptrdiff_t dop = (ptrdiff_t)dt * (ptrdiff_t)tstr2;

    // group loader: group grp covers steps {ta, ta+dt}
    f32x2 xA[6], xB[6];
    auto ldg = [&](int grp, f32x2* d){
        const int ta = dir ? (NT-1 - 2*grp) : (2*grp);
        const f32x2* pa = xp + (size_t)ta*3;
        const f32x2* pb = xp + (size_t)(ta+dt)*3;
        d[0]=pa[0]; d[1]=pa[1]; d[2]=pa[2];
        d[3]=pb[0]; d[4]=pb[1]; d[5]=pb[2];
    };

    float hoA[3];
    auto STEP = [&](const f32x2* xv){
        f32x2 h2_0{ho[0],ho[1]}, h2_1{ho[2],hx[0]}, h2_2{hx[1],hx[2]};
        float a[3];
#pragma unroll
        for (int i=0;i<3;++i){
            f32x2 acc = pkmul(Wx2[i][0], xv[0]);
            pkfma(acc, Wx2[i][1], xv[1]);
            pkfma(acc, Wx2[i][2], xv[2]);
            pkfma(acc, Uh2[i][0], h2_0);
            pkfma(acc, Uh2[i][1], h2_1);
            pkfma(acc, Uh2[i][2], h2_2);
            const float s = acc.x + acc.y;
            const float arg = fmaf(cE, s, cEb[i]);
            a[i] = fmaf(cM, rcp_(1.0f + exp2_(arg)), cB);
        }
        cell_update(a, cc, ho, g);
#pragma unroll
        for (int i=0;i<3;++i) hx[i] = swz4(ho[i]);
    };

    auto GROUP = [&](const f32x2* xv){
        STEP(xv);
#pragma unroll
        for (int i=0;i<3;++i) hoA[i] = ho[i];
        STEP(xv+3);
        if (g == 0){
            // E = even-t step of the pair: fwd -> first computed (hoA), bwd -> second (ho)
            const float e0 = dir ? ho[0]  : hoA[0];
            const float e1 = dir ? ho[1]  : hoA[1];
            const float e2 = dir ? ho[2]  : hoA[2];
            const float o0 = dir ? hoA[0] : ho[0];
            const float o1 = dir ? hoA[1] : ho[1];
            const float o2 = dir ? hoA[2] : ho[2];
            u32x3 v;
            v.x = pkrtz(e0, e1);
            v.y = pkrtz(e2, o0);
            v.z = pkrtz(o1, o2);
            *(u32x3*)op = v;
        }
        op += dop;
    };

    ldg(0, xA); ldg(1, xB);
    for (int gi=0; gi<NT/2; gi+=2){
        GROUP(xA);
        { int gp = gi+2; if (gp > NT/2-1) gp = NT/2-1; ldg(gp, xA); }
        GROUP(xB);
        { int gp = gi+3; if (gp > NT/2-1) gp = NT/2-1; ldg(gp, xB); }
    }
}

// ---------------------------------------------------------------------------
// Layer 1 forward scan over the pair-packed l0 buffer + single r1 step + head.
// 1024 waves (1/SIMD). Per 2 steps: 4x dwordx3 loads, 8x v_perm to build
// per-step dot2 operands matching wh pair order (c0,c1)(c3,c4)(c2,c5)(c6,c7)
// (c9,c10)(c8,c11).
// ---------------------------------------------------------------------------
__global__ __launch_bounds__(64)
__attribute__((amdgpu_waves_per_eu(1,1)))
void lstm_l1_g8(
    const char* __restrict__ fbuf, const char* __restrict__ bbuf,
    const float* __restrict__ h0, const float* __restrict__ c0,
    const float* __restrict__ W1f, const float* __restrict__ U1f, const float* __restrict__ b1f,
    const float* __restrict__ W1b, const float* __restrict__ U1b, const float* __restrict__ b1b,
    const float* __restrict__ fcw, const float* __restrict__ fcb,
    float* __restrict__ out)
{
    const int tid = blockIdx.x*64 + threadIdx.x;
    const int q = tid & 7;
    const int b = tid >> 3;
    const int g = q & 3;
    const int m = q >> 2;

    const float cE = (g==2) ? -2.88539008177792681f : -1.44269504088896341f;
    const float cM = (g==2) ? 2.0f : 1.0f;
    const float cB = (g==2) ? -1.0f : 0.0f;

    u32 wh[3][6];
    f32x2 Uh2[3][3];
    float cEb[3];
#pragma unroll
    for (int i=0;i<3;++i){
        const int r = g*6 + 3*m + i;
        const float* Wr = W1f + r*12;
#pragma unroll
        for (int k=0;k<6;++k){
            const int c0i = (k==0)?0:(k==1)?3:(k==2)?2:(k==3)?6:(k==4)?9:8;
            const int c1i = (k==0)?1:(k==1)?4:(k==2)?5:(k==3)?7:(k==4)?10:11;
            wh[i][k] = pkrtz(Wr[c0i], Wr[c1i]);
        }
        Uh2[i][0] = f32x2{U1f[r*6+3*m+0],     U1f[r*6+3*m+1]};
        Uh2[i][1] = f32x2{U1f[r*6+3*m+2],     U1f[r*6+3*(1-m)+0]};
        Uh2[i][2] = f32x2{U1f[r*6+3*(1-m)+1], U1f[r*6+3*(1-m)+2]};
        cEb[i] = cE * b1f[r];
    }
#pragma unroll
    for (int i=0;i<3;++i){
#pragma unroll
        for (int k=0;k<6;++k) PINF(wh[i][k]);
#pragma unroll
        for (int k=0;k<3;++k) PINF(Uh2[i][k]);
        PINF(cEb[i]);
    }

    float ho[3], hx[3], cc[3];
    {
        const int base = 2*(NB*6) + b*6;
#pragma unroll
        for (int i=0;i<3;++i){
            ho[i] = h0[base+3*m+i];
            hx[i] = h0[base+3*(1-m)+i];
            cc[i] = c0[base+3*m+i];
        }
    }

    const char* pf = fbuf + (size_t)b*24;
    const char* pb = bbuf + (size_t)b*24;
    const size_t tstr2 = (size_t)NB*24;

    u32 FA[6], BA[6], FB[6], BB[6];
    auto loadG = [&](int grp, u32* F, u32* Bv){
        const char* fp_ = pf + (size_t)grp*tstr2;
        const char* bp_ = pb + (size_t)grp*tstr2;
        u32x3 a0 = *(const u32x3*)(fp_);
        u32x3 a1 = *(const u32x3*)(fp_+12);
        u32x3 c0v = *(const u32x3*)(bp_);
        u32x3 c1v = *(const u32x3*)(bp_+12);
        F[0]=a0.x; F[1]=a0.y; F[2]=a0.z; F[3]=a1.x; F[4]=a1.y; F[5]=a1.z;
        Bv[0]=c0v.x; Bv[1]=c0v.y; Bv[2]=c0v.z; Bv[3]=c1v.x; Bv[4]=c1v.y; Bv[5]=c1v.z;
    };

    auto STEPd = [&](const u32 d[6]){
        f32x2 h2_0{ho[0],ho[1]}, h2_1{ho[2],hx[0]}, h2_2{hx[1],hx[2]};
        float a[3];
#pragma unroll
        for (int i=0;i<3;++i){
            float s = dot2u(wh[i][0], d[0], 0.0f);
#pragma unroll
            for (int k=1;k<6;++k) s = dot2u(wh[i][k], d[k], s);
            f32x2 acc = pkmul(Uh2[i][0], h2_0);
            pkfma(acc, Uh2[i][1], h2_1);
            pkfma(acc, Uh2[i][2], h2_2);
            const float z = s + acc.x + acc.y;
            const float arg = fmaf(cE, z, cEb[i]);
            a[i] = fmaf(cM, rcp_(1.0f + exp2_(arg)), cB);
        }
        cell_update(a, cc, ho, g);
#pragma unroll
        for (int i=0;i<3;++i) hx[i] = swz4(ho[i]);
    };

    auto GROUP = [&](const u32* F, const u32* Bv){
        u32 d[6];
        // even step
        d[0] = F[0];
        d[1] = F[3];
        d[2] = __builtin_amdgcn_perm(F[4], F[1], SEL_LL);
        d[3] = Bv[0];
        d[4] = Bv[3];
        d[5] = __builtin_amdgcn_perm(Bv[4], Bv[1], SEL_LL);
        STEPd(d);
        // odd step
        d[0] = __builtin_amdgcn_perm(F[2], F[1], SEL_HL);
        d[1] = __builtin_amdgcn_perm(F[5], F[4], SEL_HL);
        d[2] = __builtin_amdgcn_perm(F[5], F[2], SEL_HH);
        d[3] = __builtin_amdgcn_perm(Bv[2], Bv[1], SEL_HL);
        d[4] = __builtin_amdgcn_perm(Bv[5], Bv[4], SEL_HL);
        d[5] = __builtin_amdgcn_perm(Bv[5], Bv[2], SEL_HH);
        STEPd(d);
    };

    loadG(0, FA, BA); loadG(1, FB, BB);
    for (int gi=0; gi<NT/2; gi+=2){
        GROUP(FA, BA);
        { int gp = gi+2; if (gp > NT/2-1) gp = NT/2-1; loadG(gp, FA, BA); }
        GROUP(FB, BB);
        { int gp = gi+3; if (gp > NT/2-1) gp = NT/2-1; loadG(gp, FB, BB); }
    }
    // FB/BB hold group 255 (steps 510,511); (ho,hx) == f1[511]

    float in[12];
    in[0]=upk_hi(FB[1]); in[1]=upk_lo(FB[2]); in[2]=upk_hi(FB[2]);
    in[3]=upk_hi(FB[4]); in[4]=upk_lo(FB[5]); in[5]=upk_hi(FB[5]);
    in[6]=upk_hi(BB[1]); in[7]=upk_lo(BB[2]); in[8]=upk_hi(BB[2]);
    in[9]=upk_hi(BB[4]); in[10]=upk_lo(BB[5]); in[11]=upk_hi(BB[5]);

    // ---- r1: single reverse-direction step at t = NT-1 ----
    const int base3 = 3*(NB*6) + b*6;
    float hr[6];
#pragma unroll
    for (int j=0;j<6;++j) hr[j] = h0[base3 + j];
    float cr[3];
#pragma unroll
    for (int i=0;i<3;++i) cr[i] = c0[base3 + 3*m + i];

    float a[3];
#pragma unroll
    for (int i=0;i<3;++i){
        const int r = g*6 + 3*m + i;
        float acc = b1b[r];
#pragma unroll
        for (int k=0;k<12;++k) acc = fmaf(W1b[r*12+k], in[k], acc);
#pragma unroll
        for (int j=0;j<6;++j)  acc = fmaf(U1b[r*6+j], hr[j], acc);
        a[i] = fmaf(cM, rcp_(1.0f + exp2_(cE*acc)), cB);
    }
    float r1o[3];
    cell_update(a, cr, r1o, g);
    float r1x[3];
#pragma unroll
    for (int i=0;i<3;++i) r1x[i] = swz4(r1o[i]);

    // ---- head ----
    if (g == 0){
#pragma unroll
        for (int i=0;i<3;++i){
            const int r = 3*m + i;
            float acc = fcb[r];
#pragma unroll
            for (int k=0;k<3;++k){
                acc = fmaf(fcw[r*12 + 3*m + k],         fmaxf(ho[k],0.f), acc);
                acc = fmaf(fcw[r*12 + 3*(1-m) + k],     fmaxf(hx[k],0.f), acc);
                acc = fmaf(fcw[r*12 + 6 + 3*m + k],     fmaxf(r1o[k],0.f), acc);
                acc = fmaf(fcw[r*12 + 6 + 3*(1-m) + k], fmaxf(r1x[k],0.f), acc);
            }
            out[b*6 + r] = acc;
        }
    }
}

extern "C" void kernel_launch(void* const* d_in, const int* in_sizes, int n_in,
                              void* d_out, int out_size, void* d_ws, size_t ws_size,
                              hipStream_t stream)
{
    (void)in_sizes; (void)n_in; (void)out_size; (void)ws_size;
    const float* x    = (const float*)d_in[0];
    const float* h0   = (const float*)d_in[1];
    const float* c0   = (const float*)d_in[2];
    const float* W0f  = (const float*)d_in[3];
    const float* U0f  = (const float*)d_in[4];
    const float* b0f  = (const float*)d_in[5];
    const float* W0b  = (const float*)d_in[6];
    const float* U0b  = (const float*)d_in[7];
    const float* b0b  = (const float*)d_in[8];
    const float* W1f  = (const float*)d_in[9];
    const float* U1f  = (const float*)d_in[10];
    const float* b1f  = (const float*)d_in[11];
    const float* W1b  = (const float*)d_in[12];
    const float* U1b  = (const float*)d_in[13];
    const float* b1b  = (const float*)d_in[14];
    const float* fcw  = (const float*)d_in[15];
    const float* fcb  = (const float*)d_in[16];
    float* out = (float*)d_out;
    char* ws = (char*)d_ws;

    char* fbuf = ws;
    char* bbuf = ws + (size_t)(NT/2)*NB*24;

    lstm_l0_g8<<<dim3(2048), dim3(64), 0, stream>>>(x, h0, c0, W0f, U0f, b0f, W0b, U0b, b0b, fbuf, bbuf);
    lstm_l1_g8<<<dim3(1024), dim3(64), 0, stream>>>(fbuf, bbuf, h0, c0, W1f, U1f, b1f, W1b, U1b, b1b, fcw, fcb, out);
}

// Round 12
// 348.375 us; speedup vs baseline: 1.3249x; 1.0485x over previous
//
#include <hip/hip_runtime.h>

#define NB 8192
#define NT 512

typedef unsigned int u32;
typedef unsigned short u16;
typedef float f32x2 __attribute__((ext_vector_type(2)));
typedef u32 u32x3 __attribute__((ext_vector_type(3)));
typedef _Float16 h16x2 __attribute__((ext_vector_type(2)));

__device__ __forceinline__ float rcp_(float x){ return __builtin_amdgcn_rcpf(x); }
__device__ __forceinline__ float exp2_(float x){ return __builtin_amdgcn_exp2f(x); }
__device__ __forceinline__ float tanh_(float x){ return 1.0f - 2.0f*rcp_(1.0f + exp2_(2.88539008177792681f*x)); }

#define PINF(v)  asm volatile("" : "+v"(v))

#define QP_XOR2 0x4E
#define QP_ROT1 0x39
#define QP_ROT3 0x93
#define QP_BC0  0x00
#define QP_BC1  0x55
#define QP_BC3  0xFF
template<int C>
__device__ __forceinline__ float dppf(float x){
    return __int_as_float(__builtin_amdgcn_update_dpp(0, __float_as_int(x), C, 0xF, 0xF, true));
}
// lane^4 exchange, pure VALU (validated R10/R11)
__device__ __forceinline__ float swz4(float x){
    int v = __builtin_amdgcn_update_dpp(__float_as_int(x), __float_as_int(x), 0x104, 0xF, 0x5, false);
    v     = __builtin_amdgcn_update_dpp(v,                 __float_as_int(x), 0x114, 0xF, 0xA, false);
    return __int_as_float(v);
}
__device__ __forceinline__ u32 swz4u(u32 x){
    int v = __builtin_amdgcn_update_dpp((int)x, (int)x, 0x104, 0xF, 0x5, false);
    v     = __builtin_amdgcn_update_dpp(v,      (int)x, 0x114, 0xF, 0xA, false);
    return (u32)v;
}

__device__ __forceinline__ float upkh(u16 v){ _Float16 h; __builtin_memcpy(&h,&v,2); return (float)h; }
__device__ __forceinline__ float upk_lo(u32 v){ return upkh((u16)(v&0xffffu)); }
__device__ __forceinline__ float upk_hi(u32 v){ return upkh((u16)(v>>16)); }
__device__ __forceinline__ u32 pkrtz(float a, float b){
    auto p = __builtin_amdgcn_cvt_pkrtz(a, b);
    return __builtin_bit_cast(u32, p);
}

__device__ __forceinline__ float dot2f(h16x2 a, h16x2 b, float c){
#if __has_builtin(__builtin_amdgcn_fdot2)
    return __builtin_amdgcn_fdot2(a, b, c, false);
#else
    return fmaf((float)a.x, (float)b.x, fmaf((float)a.y, (float)b.y, c));
#endif
}
__device__ __forceinline__ float dot2u(u32 w, u32 d, float c){
    return dot2f(__builtin_bit_cast(h16x2, w), __builtin_bit_cast(h16x2, d), c);
}

// v_perm_b32: __builtin_amdgcn_perm(a,b,sel): b=bytes0-3, a=bytes4-7; res byte i = comb[sel byte i]
#define SEL_LL 0x05040100u  // lo16 = b.lo16, hi16 = a.lo16
#define SEL_HL 0x05040302u  // lo16 = b.hi16, hi16 = a.lo16

// ---------------------------------------------------------------------------
// 8-lane-per-seq: q=lane&7; gate g=q&3 (0=i,1=f,2=g,3=o); half m=q>>2.
// cell_update via quad broadcasts (validated R10/R11).
// ---------------------------------------------------------------------------
__device__ __forceinline__ void cell_update(const float a[3], float c[3], float ho[3], int g){
    float ov[3];
#pragma unroll
    for (int i=0;i<3;++i){
        const float t   = dppf<QP_XOR2>(a[i]);
        const float u   = a[i]*t;
        const float ig  = dppf<QP_BC0>(u);
        const float fc  = a[i]*c[i];
        const float fcb = dppf<QP_BC1>(fc);
        c[i]  = ig + fcb;
        ov[i] = dppf<QP_BC3>(a[i]);
    }
    const float cg = (g==1) ? c[1] : ((g==2) ? c[2] : c[0]);
    const float tg = tanh_(cg);
    const float w1 = dppf<QP_ROT1>(tg);
    const float w2 = dppf<QP_XOR2>(tg);
    const float w3 = dppf<QP_ROT3>(tg);
#pragma unroll
    for (int j=0;j<3;++j){
        const int r = (j - g) & 3;
        const float lo = (r & 1) ? w1 : tg;
        const float hi = (r & 1) ? w3 : w2;
        ho[j] = ov[j] * ((r & 2) ? hi : lo);
    }
}

// Pack h state: pA=(h0,h1), pB=(h2,h2); qA=swz4(pA)=(hx0,hx1), qB=(hx2,hx2);
// pr1=(h2,hx0), pr2=(hx1,hx2). U-pair order: (u3m,u3m+1)(u3m+2,ux0)(ux1,ux2).
__device__ __forceinline__ void packh(const float ho[3], u32& pA, u32& pB, u32& pr1, u32& pr2){
    pA = pkrtz(ho[0], ho[1]);
    pB = pkrtz(ho[2], ho[2]);
    const u32 qA = swz4u(pA);
    const u32 qB = swz4u(pB);
    pr1 = __builtin_amdgcn_perm(qA, pB, SEL_LL);
    pr2 = __builtin_amdgcn_perm(qB, qA, SEL_HL);
}

// ---------------------------------------------------------------------------
// Layer 0, both directions. 2048 waves (2/SIMD). fp16 dot2 dense; weights
// pre-scaled by cE, bias seeds the chain. Pair-packed dwordx3 store per
// 2 steps (layout identical to R11).
// ---------------------------------------------------------------------------
__global__ __launch_bounds__(64)
__attribute__((amdgpu_waves_per_eu(2,2)))
void lstm_l0_g8(
    const float* __restrict__ x,
    const float* __restrict__ h0, const float* __restrict__ c0,
    const float* __restrict__ Wf, const float* __restrict__ Uf, const float* __restrict__ bf,
    const float* __restrict__ Wb, const float* __restrict__ Ub, const float* __restrict__ bb,
    char* __restrict__ fbuf, char* __restrict__ bbuf)
{
    const int tid = blockIdx.x*64 + threadIdx.x;
    const int q   = tid & 7;
    const int e   = tid >> 3;
    const int b   = e & (NB-1);
    const int dir = e >> 13;
    const int g   = q & 3;
    const int m   = q >> 2;

    const float* W  = dir ? Wb : Wf;
    const float* U  = dir ? Ub : Uf;
    const float* bi = dir ? bb : bf;

    const float cE = (g==2) ? -2.88539008177792681f : -1.44269504088896341f;
    const float cM = (g==2) ? 2.0f : 1.0f;
    const float cB = (g==2) ? -1.0f : 0.0f;

    u32 whx[3][3], whu[3][3];
    float cEb[3];
#pragma unroll
    for (int i=0;i<3;++i){
        const int r = g*6 + 3*m + i;
#pragma unroll
        for (int k=0;k<3;++k) whx[i][k] = pkrtz(cE*W[r*6+2*k], cE*W[r*6+2*k+1]);
        whu[i][0] = pkrtz(cE*U[r*6+3*m+0],     cE*U[r*6+3*m+1]);
        whu[i][1] = pkrtz(cE*U[r*6+3*m+2],     cE*U[r*6+3*(1-m)+0]);
        whu[i][2] = pkrtz(cE*U[r*6+3*(1-m)+1], cE*U[r*6+3*(1-m)+2]);
        cEb[i] = cE * bi[r];
    }
#pragma unroll
    for (int i=0;i<3;++i){
#pragma unroll
        for (int k=0;k<3;++k){ PINF(whx[i][k]); PINF(whu[i][k]); }
        PINF(cEb[i]);
    }

    float cc[3];
    u32 pA, pB, pr1, pr2;
    {
        const int base = dir*(NB*6) + b*6;
        float ho[3];
#pragma unroll
        for (int i=0;i<3;++i){
            ho[i] = h0[base+3*m+i];
            cc[i] = c0[base+3*m+i];
        }
        packh(ho, pA, pB, pr1, pr2);
    }

    const f32x2* xp = (const f32x2*)(x + (size_t)b*(NT*6));
    const int dt = dir ? -1 : 1;

    const size_t tstr2 = (size_t)NB*24;
    char* op = (dir ? bbuf : fbuf) + (size_t)b*24 + m*12 + (size_t)(dir ? (NT/2-1) : 0)*tstr2;
    const ptrdiff_t dop = (ptrdiff_t)dt * (ptrdiff_t)tstr2;

    f32x2 xA[6], xB[6];
    auto ldg = [&](int grp, f32x2* d){
        const int ta = dir ? (NT-1 - 2*grp) : (2*grp);
        const f32x2* pa = xp + (size_t)ta*3;
        const f32x2* pb = xp + (size_t)(ta+dt)*3;
        d[0]=pa[0]; d[1]=pa[1]; d[2]=pa[2];
        d[3]=pb[0]; d[4]=pb[1]; d[5]=pb[2];
    };

    auto STEP = [&](const f32x2* xv){
        u32 px0 = pkrtz(xv[0].x, xv[0].y);
        u32 px1 = pkrtz(xv[1].x, xv[1].y);
        u32 px2 = pkrtz(xv[2].x, xv[2].y);
        float a[3];
#pragma unroll
        for (int i=0;i<3;++i){
            float s = dot2u(whu[i][2], pr2, cEb[i]);
            s = dot2u(whu[i][1], pr1, s);
            s = dot2u(whu[i][0], pA,  s);
            s = dot2u(whx[i][2], px2, s);
            s = dot2u(whx[i][1], px1, s);
            s = dot2u(whx[i][0], px0, s);
            a[i] = fmaf(cM, rcp_(1.0f + exp2_(s)), cB);
        }
        float ho[3];
        cell_update(a, cc, ho, g);
        packh(ho, pA, pB, pr1, pr2);
    };

    auto GROUP = [&](const f32x2* xv){
        STEP(xv);
        const u32 sE0 = pA, sE1 = pB;   // first-computed step of the pair
        STEP(xv+3);
        if (g == 0){
            // E = even timestep: fwd -> first (sE), bwd -> second (current)
            u32x3 v;
            if (!dir){
                v.x = sE0;
                v.y = __builtin_amdgcn_perm(pA, sE1, SEL_LL);   // (h2E, h0O)
                v.z = __builtin_amdgcn_perm(pB, pA, SEL_HL);    // (h1O, h2O)
            } else {
                v.x = pA;
                v.y = __builtin_amdgcn_perm(sE0, pB, SEL_LL);   // (h2E, h0O)
                v.z = __builtin_amdgcn_perm(sE1, sE0, SEL_HL);  // (h1O, h2O)
            }
            *(u32x3*)op = v;
        }
        op += dop;
    };

    ldg(0, xA); ldg(1, xB);
    for (int gi=0; gi<NT/2; gi+=2){
        GROUP(xA);
        { int gp = gi+2; if (gp > NT/2-1) gp = NT/2-1; ldg(gp, xA); }
        GROUP(xB);
        { int gp = gi+3; if (gp > NT/2-1) gp = NT/2-1; ldg(gp, xB); }
    }
}

// ---------------------------------------------------------------------------
// Layer 1 forward scan (all-fp16 dot2 dense, 2-acc chains) + r1 step + head.
// 1024 waves (1/SIMD).
// ---------------------------------------------------------------------------
__global__ __launch_bounds__(64)
__attribute__((amdgpu_waves_per_eu(1,1)))
void lstm_l1_g8(
    const char* __restrict__ fbuf, const char* __restrict__ bbuf,
    const float* __restrict__ h0, const float* __restrict__ c0,
    const float* __restrict__ W1f, const float* __restrict__ U1f, const float* __restrict__ b1f,
    const float* __restrict__ W1b, const float* __restrict__ U1b, const float* __restrict__ b1b,
    const float* __restrict__ fcw, const float* __restrict__ fcb,
    float* __restrict__ out)
{
    const int tid = blockIdx.x*64 + threadIdx.x;
    const int q = tid & 7;
    const int b = tid >> 3;
    const int g = q & 3;
    const int m = q >> 2;

    const float cE = (g==2) ? -2.88539008177792681f : -1.44269504088896341f;
    const float cM = (g==2) ? 2.0f : 1.0f;
    const float cB = (g==2) ? -1.0f : 0.0f;

    // input-weight pairs matching buffer dwords: (c0,c1)(c3,c4)(c2,c5)(c6,c7)(c9,c10)(c8,c11)
    u32 wh[3][6], whu[3][3];
    float cEb[3];
#pragma unroll
    for (int i=0;i<3;++i){
        const int r = g*6 + 3*m + i;
        const float* Wr = W1f + r*12;
#pragma unroll
        for (int k=0;k<6;++k){
            const int c0i = (k==0)?0:(k==1)?3:(k==2)?2:(k==3)?6:(k==4)?9:8;
            const int c1i = (k==0)?1:(k==1)?4:(k==2)?5:(k==3)?7:(k==4)?10:11;
            wh[i][k] = pkrtz(cE*Wr[c0i], cE*Wr[c1i]);
        }
        whu[i][0] = pkrtz(cE*U1f[r*6+3*m+0],     cE*U1f[r*6+3*m+1]);
        whu[i][1] = pkrtz(cE*U1f[r*6+3*m+2],     cE*U1f[r*6+3*(1-m)+0]);
        whu[i][2] = pkrtz(cE*U1f[r*6+3*(1-m)+1], cE*U1f[r*6+3*(1-m)+2]);
        cEb[i] = cE * b1f[r];
    }
#pragma unroll
    for (int i=0;i<3;++i){
#pragma unroll
        for (int k=0;k<6;++k) PINF(wh[i][k]);
#pragma unroll
        for (int k=0;k<3;++k) PINF(whu[i][k]);
        PINF(cEb[i]);
    }

    float cc[3], ho[3];
    u32 pA, pB, pr1, pr2;
    {
        const int base = 2*(NB*6) + b*6;
#pragma unroll
        for (int i=0;i<3;++i){
            ho[i] = h0[base+3*m+i];
            cc[i] = c0[base+3*m+i];
        }
        packh(ho, pA, pB, pr1, pr2);
    }

    const char* pf = fbuf + (size_t)b*24;
    const char* pb = bbuf + (size_t)b*24;
    const size_t tstr2 = (size_t)NB*24;

    u32 FA[6], BA[6], FB[6], BB[6];
    auto loadG = [&](int grp, u32* F, u32* Bv){
        const char* fp_ = pf + (size_t)grp*tstr2;
        const char* bp_ = pb + (size_t)grp*tstr2;
        u32x3 a0 = *(const u32x3*)(fp_);
        u32x3 a1 = *(const u32x3*)(fp_+12);
        u32x3 c0v = *(const u32x3*)(bp_);
        u32x3 c1v = *(const u32x3*)(bp_+12);
        F[0]=a0.x; F[1]=a0.y; F[2]=a0.z; F[3]=a1.x; F[4]=a1.y; F[5]=a1.z;
        Bv[0]=c0v.x; Bv[1]=c0v.y; Bv[2]=c0v.z; Bv[3]=c1v.x; Bv[4]=c1v.y; Bv[5]=c1v.z;
    };

    auto STEPd = [&](const u32 d[6]){
        float a[3];
#pragma unroll
        for (int i=0;i<3;++i){
            // two independent chains (latency)
            float sA = dot2u(wh[i][0], d[0], 0.0f);
            sA = dot2u(wh[i][2], d[2], sA);
            sA = dot2u(wh[i][4], d[4], sA);
            sA = dot2u(whu[i][0], pA, sA);
            float sB = dot2u(wh[i][1], d[1], cEb[i]);
            sB = dot2u(wh[i][3], d[3], sB);
            sB = dot2u(wh[i][5], d[5], sB);
            sB = dot2u(whu[i][1], pr1, sB);
            sB = dot2u(whu[i][2], pr2, sB);
            const float s = sA + sB;
            a[i] = fmaf(cM, rcp_(1.0f + exp2_(s)), cB);
        }
        cell_update(a, cc, ho, g);
        packh(ho, pA, pB, pr1, pr2);
    };

    auto GROUP = [&](const u32* F, const u32* Bv){
        u32 d[6];
        d[0] = F[0];
        d[1] = F[3];
        d[2] = __builtin_amdgcn_perm(F[4], F[1], SEL_LL);
        d[3] = Bv[0];
        d[4] = Bv[3];
        d[5] = __builtin_amdgcn_perm(Bv[4], Bv[1], SEL_LL);
        STEPd(d);
        d[0] = __builtin_amdgcn_perm(F[2], F[1], SEL_HL);
        d[1] = __builtin_amdgcn_perm(F[5], F[4], SEL_HL);
        d[2] = __builtin_amdgcn_perm(F[5], F[2], 0x07060302u);
        d[3] = __builtin_amdgcn_perm(Bv[2], Bv[1], SEL_HL);
        d[4] = __builtin_amdgcn_perm(Bv[5], Bv[4], SEL_HL);
        d[5] = __builtin_amdgcn_perm(Bv[5], Bv[2], 0x07060302u);
        STEPd(d);
    };

    loadG(0, FA, BA); loadG(1, FB, BB);
    for (int gi=0; gi<NT/2; gi+=2){
        GROUP(FA, BA);
        { int gp = gi+2; if (gp > NT/2-1) gp = NT/2-1; loadG(gp, FA, BA); }
        GROUP(FB, BB);
        { int gp = gi+3; if (gp > NT/2-1) gp = NT/2-1; loadG(gp, FB, BB); }
    }
    // (ho, cc) == f1[511]; FB/BB hold group 255 for the r1 input

    float hx[3];
#pragma unroll
    for (int i=0;i<3;++i) hx[i] = swz4(ho[i]);

    float in[12];
    in[0]=upk_hi(FB[1]); in[1]=upk_lo(FB[2]); in[2]=upk_hi(FB[2]);
    in[3]=upk_hi(FB[4]); in[4]=upk_lo(FB[5]); in[5]=upk_hi(FB[5]);
    in[6]=upk_hi(BB[1]); in[7]=upk_lo(BB[2]); in[8]=upk_hi(BB[2]);
    in[9]=upk_hi(BB[4]); in[10]=upk_lo(BB[5]); in[11]=upk_hi(BB[5]);

    // ---- r1: single reverse-direction step at t = NT-1 (f32 math) ----
    const int base3 = 3*(NB*6) + b*6;
    float hr[6];
#pragma unroll
    for (int j=0;j<6;++j) hr[j] = h0[base3 + j];
    float cr[3];
#pragma unroll
    for (int i=0;i<3;++i) cr[i] = c0[base3 + 3*m + i];

    float a[3];
#pragma unroll
    for (int i=0;i<3;++i){
        const int r = g*6 + 3*m + i;
        float acc = b1b[r];
#pragma unroll
        for (int k=0;k<12;++k) acc = fmaf(W1b[r*12+k], in[k], acc);
#pragma unroll
        for (int j=0;j<6;++j)  acc = fmaf(U1b[r*6+j], hr[j], acc);
        a[i] = fmaf(cM, rcp_(1.0f + exp2_(cE*acc)), cB);
    }
    float r1o[3];
    cell_update(a, cr, r1o, g);
    float r1x[3];
#pragma unroll
    for (int i=0;i<3;++i) r1x[i] = swz4(r1o[i]);

    // ---- head ----
    if (g == 0){
#pragma unroll
        for (int i=0;i<3;++i){
            const int r = 3*m + i;
            float acc = fcb[r];
#pragma unroll
            for (int k=0;k<3;++k){
                acc = fmaf(fcw[r*12 + 3*m + k],         fmaxf(ho[k],0.f), acc);
                acc = fmaf(fcw[r*12 + 3*(1-m) + k],     fmaxf(hx[k],0.f), acc);
                acc = fmaf(fcw[r*12 + 6 + 3*m + k],     fmaxf(r1o[k],0.f), acc);
                acc = fmaf(fcw[r*12 + 6 + 3*(1-m) + k], fmaxf(r1x[k],0.f), acc);
            }
            out[b*6 + r] = acc;
        }
    }
}

extern "C" void kernel_launch(void* const* d_in, const int* in_sizes, int n_in,
                              void* d_out, int out_size, void* d_ws, size_t ws_size,
                              hipStream_t stream)
{
    (void)in_sizes; (void)n_in; (void)out_size; (void)ws_size;
    const float* x    = (const float*)d_in[0];
    const float* h0   = (const float*)d_in[1];
    const float* c0   = (const float*)d_in[2];
    const float* W0f  = (const float*)d_in[3];
    const float* U0f  = (const float*)d_in[4];
    const float* b0f  = (const float*)d_in[5];
    const float* W0b  = (const float*)d_in[6];
    const float* U0b  = (const float*)d_in[7];
    const float* b0b  = (const float*)d_in[8];
    const float* W1f  = (const float*)d_in[9];
    const float* U1f  = (const float*)d_in[10];
    const float* b1f  = (const float*)d_in[11];
    const float* W1b  = (const float*)d_in[12];
    const float* U1b  = (const float*)d_in[13];
    const float* b1b  = (const float*)d_in[14];
    const float* fcw  = (const float*)d_in[15];
    const float* fcb  = (const float*)d_in[16];
    float* out = (float*)d_out;
    char* ws = (char*)d_ws;

    char* fbuf = ws;
    char* bbuf = ws + (size_t)(NT/2)*NB*24;

    lstm_l0_g8<<<dim3(2048), dim3(64), 0, stream>>>(x, h0, c0, W0f, U0f, b0f, W0b, U0b, b0b, fbuf, bbuf);
    lstm_l1_g8<<<dim3(1024), dim3(64), 0, stream>>>(fbuf, bbuf, h0, c0, W1f, U1f, b1f, W1b, U1b, b1b, fcw, fcb, out);
}